// Round 14
// baseline (148.697 us; speedup 1.0000x reference)
//
#include <hip/hip_runtime.h>
#include <stdint.h>

#define NTOT 8192
#define BHALF 4096
#define DZ 512
#define DC 128
#define TEMPV 0.5f
#define FIXM 16.0f
#define LOG2E 1.44269504f
#define FM2 23.08312065f   // FIXM * LOG2E
#define SCALE1 0x7F7F7F7F  // e8m0 unit scales
#define NBLKT 1056         // triangle blocks: sum_{rb<32}(64-2rb)

typedef __attribute__((ext_vector_type(4))) float f32x4;
typedef __attribute__((ext_vector_type(4))) float floatx4;
typedef __attribute__((ext_vector_type(2))) unsigned long ulong2v;  // 16B chunk
typedef __attribute__((ext_vector_type(8))) int int8v;              // 32B MFMA operand
typedef __attribute__((ext_vector_type(4))) unsigned int uint4v;

#define MFMAS(a, b, c) \
  __builtin_amdgcn_mfma_scale_f32_16x16x128_f8f6f4((a), (b), (c), 0, 0, 0, SCALE1, 0, SCALE1)

__device__ __forceinline__ uint32_t pk4_e4m3(float f0, float f1, float f2, float f3) {
  int w = 0;
  w = __builtin_amdgcn_cvt_pk_fp8_f32(f0, f1, w, false);
  w = __builtin_amdgcn_cvt_pk_fp8_f32(f2, f3, w, true);
  return (uint32_t)w;
}

__device__ __forceinline__ int8v mk8(ulong2v lo, ulong2v hi) {
  int8v r;
  ((ulong2v*)&r)[0] = lo;
  ((ulong2v*)&r)[1] = hi;
  return r;
}

// ---------------- convert: fp32 -> fp8 e4m3 (frag-pair-tiled) + exact pos dots ----------------
// Blocks 0..1279: 16B chunk ((ct*KP+cc)*64+lane): bytes 0..7 = x[ct*16+ln][cc*64+lq*8..+8),
// bytes 8..15 same +32 in k. A-frag layout (row-tile ct) == B-frag layout (col-tile ct).
// Chunk-pair (2kq,2kq+1) = 32B operand of the K=128 scaled MFMA (consistent k-permutation
// for A and B -> dot unaffected). Blocks 1280..1535: pos2[p] = 2*dot(z_i[p], z_j[p]) fp32.
__global__ void convert_kernel(const float* __restrict__ z_i, const float* __restrict__ z_j,
                               const float* __restrict__ c_i, const float* __restrict__ c_j,
                               uint8_t* __restrict__ zbT, uint8_t* __restrict__ cbT,
                               float* __restrict__ pos2, float* __restrict__ out) {
  const int ZC = NTOT * DZ / 16;   // 262144 chunks
  const int CC = NTOT * DC / 16;   // 65536

  if (blockIdx.x >= 1280) {
    if (blockIdx.x == 1280 && threadIdx.x == 0) out[0] = 0.0f;
    const int wv   = (blockIdx.x - 1280) * 4 + (threadIdx.x >> 6);
    const int lane = threadIdx.x & 63;
#pragma unroll
    for (int q = 0; q < 4; ++q) {
      const int p = wv * 4 + q;
      const float* a = z_i + (size_t)p * DZ + lane * 8;
      const float* b = z_j + (size_t)p * DZ + lane * 8;
      floatx4 a0 = *(const floatx4*)a, a1 = *(const floatx4*)(a + 4);
      floatx4 b0 = *(const floatx4*)b, b1 = *(const floatx4*)(b + 4);
      float d = a0[0]*b0[0] + a0[1]*b0[1] + a0[2]*b0[2] + a0[3]*b0[3]
              + a1[0]*b1[0] + a1[1]*b1[1] + a1[2]*b1[2] + a1[3]*b1[3];
#pragma unroll
      for (int off = 1; off < 64; off <<= 1) d += __shfl_xor(d, off);
      if (lane == 0) pos2[p] = 2.0f * d;
    }
    return;
  }

  int i = blockIdx.x * blockDim.x + threadIdx.x;
  const float* src;
  uint8_t* dst;
  int k0;
  if (i < ZC) {
    int lane = i & 63, g = i >> 6;
    int ct = g >> 3, cc = g & 7;
    int ln = lane & 15, lq = lane >> 4;
    int row = ct * 16 + ln;
    k0 = cc * 64 + lq * 8;
    src = (row < BHALF) ? (z_i + (size_t)row * DZ) : (z_j + (size_t)(row - BHALF) * DZ);
    dst = zbT + (size_t)i * 16;
  } else {
    int i2 = i - ZC;
    int lane = i2 & 63, g = i2 >> 6;
    int ct = g >> 1, cc = g & 1;
    int ln = lane & 15, lq = lane >> 4;
    int row = ct * 16 + ln;
    k0 = cc * 64 + lq * 8;
    src = (row < BHALF) ? (c_i + (size_t)row * DC) : (c_j + (size_t)(row - BHALF) * DC);
    dst = cbT + (size_t)i2 * 16;
  }
  floatx4 a0 = *(const floatx4*)(src + k0);
  floatx4 a1 = *(const floatx4*)(src + k0 + 4);
  floatx4 b0 = *(const floatx4*)(src + k0 + 32);
  floatx4 b1 = *(const floatx4*)(src + k0 + 36);
  uint4v o;
  o.x = pk4_e4m3(a0[0], a0[1], a0[2], a0[3]);
  o.y = pk4_e4m3(a1[0], a1[1], a1[2], a1[3]);
  o.z = pk4_e4m3(b0[0], b0[1], b0[2], b0[3]);
  o.w = pk4_e4m3(b1[0], b1[1], b1[2], b1[3]);
  *(uint4v*)dst = o;
}

// stage col-tile ct into LDS: wave w stages z chunk-group w; waves 0,1 stage c
__device__ __forceinline__ void stage_tile(const uint8_t* __restrict__ zbT,
                                           const uint8_t* __restrict__ cbT,
                                           uint8_t* zS, uint8_t* cS,
                                           int ct, int w, int lane) {
  const uint8_t* src = zbT + (((size_t)ct * 8 + w) * 64 + lane) * 16;
  __builtin_amdgcn_global_load_lds((const __attribute__((address_space(1))) void*)src,
                                   (__attribute__((address_space(3))) void*)(zS + w * 1024),
                                   16, 0, 0);
  if (w < 2) {
    const uint8_t* srcc = cbT + (((size_t)ct * 2 + w) * 64 + lane) * 16;
    __builtin_amdgcn_global_load_lds((const __attribute__((address_space(1))) void*)srcc,
                                     (__attribute__((address_space(3))) void*)(cS + w * 1024),
                                     16, 0, 0);
  }
}

// ---------------- fused symmetric flash-lse: 256x128 upper-triangle blocks ----------------
// 1056 blocks: rb in [0,32) (256 rows), cb in [2rb, 64) (128 cols). 8 waves x
// TWO 16-row A-sets (set0 = rb*256+w*16, set1 = +128) share every B-fragment
// read -> LDS traffic per entry halved vs R13. Register audit: R13 measured 48
// VGPR one-set; second set adds ~52 -> ~100 < 128 cap of (512,4). e scatters to
// row accums l0/l1 and col partials (colbuf). Diag: cb==2rb -> set0 masked
// gc<=gr, set1 skipped (lower); cb==2rb+1 -> set1 masked. Pair: cb==2rb+32+s,
// it==w, ln==lq*4+r. Plain stores RP[row][64] / CP[col][32]; no atomics.
__launch_bounds__(512, 4)
__global__ void fused_kernel(const uint8_t* __restrict__ zbT, const uint8_t* __restrict__ cbT,
                             float* __restrict__ RP, float* __restrict__ CP) {
  __shared__ __align__(16) uint8_t zS[2][8192];   // 2 x 8 KB
  __shared__ __align__(16) uint8_t cS[2][2048];   // 2 x 2 KB
  __shared__ float colbuf[8 * 128];               // 4 KB

  // decode t -> (rb, cb): S(rb) = rb*(65-rb); cb = 2rb + (t - S(rb))
  const int t = blockIdx.x;
  int rb = (int)((65.0f - __builtin_sqrtf(65.0f * 65.0f - 4.0f * (float)t)) * 0.5f);
  while (rb * (65 - rb) > t) --rb;
  while ((rb + 1) * (65 - (rb + 1)) <= t) ++rb;
  const int cb = 2 * rb + (t - rb * (65 - rb));

  const bool d0 = (cb == 2 * rb);          // set0 diagonal block (set1 = lower, skip)
  const bool d1 = (cb == 2 * rb + 1);      // set1 diagonal block
  const bool p0 = (cb == 2 * rb + 32);     // set0 pair block
  const bool p1 = (cb == 2 * rb + 33);     // set1 pair block

  const int tid  = threadIdx.x;
  const int w    = tid >> 6;      // 0..7
  const int lane = tid & 63;
  const int lq   = lane >> 4;
  const int ln   = lane & 15;

  const int row0 = rb * 256 + w * 16;      // set0 rows
  const int row1 = row0 + 128;             // set1 rows
  const int rt0  = rb * 16 + w;
  const int rt1  = rt0 + 8;

  // A operands: 2 sets x (z: 4 x v8i32, c: 1 x v8i32)
  int8v a_z0[4], a_z1[4], a_c0, a_c1;
  {
    const uint8_t* pz0 = zbT + ((size_t)rt0 * 8 * 64 + lane) * 16;
    const uint8_t* pz1 = zbT + ((size_t)rt1 * 8 * 64 + lane) * 16;
#pragma unroll
    for (int kq = 0; kq < 4; ++kq) {
      a_z0[kq] = mk8(*(const ulong2v*)(pz0 + (size_t)(2 * kq) * 1024),
                     *(const ulong2v*)(pz0 + (size_t)(2 * kq + 1) * 1024));
      a_z1[kq] = mk8(*(const ulong2v*)(pz1 + (size_t)(2 * kq) * 1024),
                     *(const ulong2v*)(pz1 + (size_t)(2 * kq + 1) * 1024));
    }
    const uint8_t* qc0 = cbT + ((size_t)rt0 * 2 * 64 + lane) * 16;
    const uint8_t* qc1 = cbT + ((size_t)rt1 * 2 * 64 + lane) * 16;
    a_c0 = mk8(*(const ulong2v*)qc0, *(const ulong2v*)(qc0 + 1024));
    a_c1 = mk8(*(const ulong2v*)qc1, *(const ulong2v*)(qc1 + 1024));
  }

  float l0[4] = {0.f, 0.f, 0.f, 0.f};
  float l1[4] = {0.f, 0.f, 0.f, 0.f};

  const int ct_base = cb * 8;
  stage_tile(zbT, cbT, zS[0], cS[0], ct_base, w, lane);
  __syncthreads();

#pragma unroll
  for (int it = 0; it < 8; ++it) {
    const int cur = it & 1;
    if (it + 1 < 8)
      stage_tile(zbT, cbT, zS[cur ^ 1], cS[cur ^ 1], ct_base + it + 1, w, lane);

    const bool do0 = !(d0 && it < w);            // set0: skip tiles fully below diag
    const bool do1 = !(d0 || (d1 && it < w));    // set1: skip whole block if d0

    float lcv = 0.0f;
    if (do0 || do1) {
      const uint8_t* zb  = zS[cur];
      const uint8_t* cb_ = cS[cur];

      f32x4 ac0 = {0.f,0.f,0.f,0.f}, ac1 = {0.f,0.f,0.f,0.f};
      {
        const int8v b = mk8(*(const ulong2v*)(cb_ + lane * 16),
                            *(const ulong2v*)(cb_ + 1024 + lane * 16));
        if (do0) ac0 = MFMAS(a_c0, b, ac0);
        if (do1) ac1 = MFMAS(a_c1, b, ac1);
      }
      f32x4 az0 = {0.f,0.f,0.f,0.f}, az1 = {0.f,0.f,0.f,0.f};
#pragma unroll
      for (int kq = 0; kq < 4; ++kq) {
        const int8v b = mk8(*(const ulong2v*)(zb + (2 * kq) * 1024 + lane * 16),
                            *(const ulong2v*)(zb + (2 * kq + 1) * 1024 + lane * 16));
        if (do0) az0 = MFMAS(a_z0[kq], b, az0);
        if (do1) az1 = MFMAS(a_z1[kq], b, az1);
      }

      const int gc = cb * 128 + it * 16 + ln;
      if (do0) {
        const int grb = row0 + lq * 4;
        const bool pairTile = p0 && (it == w);
#pragma unroll
        for (int r = 0; r < 4; ++r) {
          float tv = fmaxf(ac0[r], TEMPV);
          float sv = az0[r] * __builtin_amdgcn_rcpf(tv);
          float e  = __builtin_amdgcn_exp2f(__builtin_fmaf(sv, LOG2E, -FM2));
          if (d0 && gc <= grb + r) e = 0.0f;
          if (pairTile && ln == lq * 4 + r) e = 0.0f;
          l0[r] += e;
          lcv += e;
        }
      }
      if (do1) {
        const int grb = row1 + lq * 4;
        const bool pairTile = p1 && (it == w);
#pragma unroll
        for (int r = 0; r < 4; ++r) {
          float tv = fmaxf(ac1[r], TEMPV);
          float sv = az1[r] * __builtin_amdgcn_rcpf(tv);
          float e  = __builtin_amdgcn_exp2f(__builtin_fmaf(sv, LOG2E, -FM2));
          if (d1 && gc <= grb + r) e = 0.0f;
          if (pairTile && ln == lq * 4 + r) e = 0.0f;
          l1[r] += e;
          lcv += e;
        }
      }
    }

    // col partial for this tile (both sets): reduce over lq, unique slot
    float v = lcv;
    v += __shfl_xor(v, 16);
    v += __shfl_xor(v, 32);
    if (lq == 0) colbuf[w * 128 + it * 16 + ln] = v;

    __syncthreads();   // protects cur buffer; drains prefetch; orders colbuf
  }

  // row partials -> RP[row][cb] (always written; skipped sets contribute 0)
#pragma unroll
  for (int r = 0; r < 4; ++r) {
    float v0 = l0[r];
    float v1 = l1[r];
#pragma unroll
    for (int off = 1; off < 16; off <<= 1) {
      v0 += __shfl_xor(v0, off);
      v1 += __shfl_xor(v1, off);
    }
    if (ln == 0) {
      RP[(size_t)(row0 + lq * 4 + r) * 64 + cb] = v0;
      RP[(size_t)(row1 + lq * 4 + r) * 64 + cb] = v1;
    }
  }

  // col partials: sum the 8 per-wave rows of colbuf -> CP[col][rb]
  if (tid < 128) {
    float s = 0.0f;
#pragma unroll
    for (int ww = 0; ww < 8; ++ww) s += colbuf[ww * 128 + tid];
    CP[(size_t)(cb * 128 + tid) * 32 + rb] = s;
  }
}

// ---------------- finalize: triangular partial merge + pos + reduction ----------------
// 512 blocks x 1024 thr; one wave per row. Row r (R2 = r>>8): negsum =
// sum_{cb>=2*R2} RP[r][cb] + sum_{rb<=R2} CP[r][rb].
__global__ void finalize_kernel(const float* __restrict__ RP, const float* __restrict__ CP,
                                const float* __restrict__ pos2, float* __restrict__ out) {
  const int tid  = threadIdx.x;
  const int w    = tid >> 6;
  const int lane = tid & 63;
  const int row  = blockIdx.x * 16 + w;
  const int R2   = row >> 8;

  float v = 0.0f;
  if (lane >= 2 * R2) v += RP[(size_t)row * 64 + lane];
  if (lane <= R2)     v += CP[(size_t)row * 32 + lane];
#pragma unroll
  for (int off = 1; off < 64; off <<= 1) v += __shfl_xor(v, off);

  __shared__ float red[16];
  if (lane == 0) {
    float pos  = pos2[row & (BHALF - 1)];
    float lneg = FIXM + __logf(v);
    float hi = fmaxf(lneg, pos), lo = fminf(lneg, pos);
    float lse = hi + __logf(1.0f + __expf(lo - hi));
    red[w] = lse - pos;
  }
  __syncthreads();
  if (tid == 0) {
    float s = 0.0f;
#pragma unroll
    for (int i = 0; i < 16; ++i) s += red[i];
    atomicAdd(out, s * (1.0f / NTOT));
  }
}

extern "C" void kernel_launch(void* const* d_in, const int* in_sizes, int n_in,
                              void* d_out, int out_size, void* d_ws, size_t ws_size,
                              hipStream_t stream) {
  const float* z_i = (const float*)d_in[0];
  const float* z_j = (const float*)d_in[1];
  const float* c_i = (const float*)d_in[2];
  const float* c_j = (const float*)d_in[3];

  uint8_t* zbT = (uint8_t*)d_ws;                        // 4 MB fp8 z (tiled)
  uint8_t* cbT = zbT + (size_t)NTOT * DZ;               // 1 MB fp8 c (tiled)
  float* RP   = (float*)(cbT + (size_t)NTOT * DC);      // 8192*64 f32 = 2 MB
  float* CP   = RP + (size_t)NTOT * 64;                 // 8192*32 f32 = 1 MB
  float* pos2 = CP + (size_t)NTOT * 32;                 // 16 KB

  convert_kernel<<<1536, 256, 0, stream>>>(z_i, z_j, c_i, c_j, zbT, cbT, pos2, (float*)d_out);
  fused_kernel<<<NBLKT, 512, 0, stream>>>(zbT, cbT, RP, CP);
  finalize_kernel<<<512, 1024, 0, stream>>>(RP, CP, pos2, (float*)d_out);
}